// Round 2
// baseline (1417.811 us; speedup 1.0000x reference)
//
#include <hip/hip_runtime.h>

#define F_IN 500
#define F_HID 16
#define F_OUT 3

// K0: compact/validate edges (input already int32 per harness) and count in-degree
__global__ void k_edges(const int* __restrict__ ei, int E, int N,
                        int* __restrict__ src32, int* __restrict__ dst32,
                        float* __restrict__ deg) {
    int e = blockIdx.x * blockDim.x + threadIdx.x;
    if (e >= E) return;
    int s = ei[e];
    int d = ei[(size_t)E + e];
    // defensive clamp: never let a bad index become an OOB atomic
    s = min(max(s, 0), N - 1);
    d = min(max(d, 0), N - 1);
    src32[e] = s;
    dst32[e] = d;
    atomicAdd(&deg[d], 1.0f);
}

// K1: dinv = rsqrt(deg + 1)  (self-loop contributes the +1)
__global__ void k_dinv(float* __restrict__ deg, int N) {
    int i = blockIdx.x * blockDim.x + threadIdx.x;
    if (i >= N) return;
    deg[i] = rsqrtf(deg[i] + 1.0f);
}

// K2: h1 = x @ W1 ; agg1 = b1 + h1 * dinv^2   (self-loop init fused)
// block = 256 (4 waves), wave handles 4 rows x 16 cols. W1^T staged in LDS.
__global__ __launch_bounds__(256) void k_gemm1(const float* __restrict__ x,
                                               const float* __restrict__ W1,
                                               const float* __restrict__ b1,
                                               const float* __restrict__ dinv,
                                               float* __restrict__ h1,
                                               float* __restrict__ agg1, int N) {
    __shared__ float w[F_HID * F_IN];  // w[j][k], 32000 B
    for (int idx = threadIdx.x; idx < F_IN * F_HID; idx += 256) {
        int k = idx >> 4, j = idx & 15;
        w[j * F_IN + k] = W1[idx];
    }
    __syncthreads();
    int wave = threadIdx.x >> 6, lane = threadIdx.x & 63;
    int rsub = lane >> 4, j = lane & 15;
    int row = blockIdx.x * 16 + wave * 4 + rsub;
    if (row >= N) return;
    const float* xr = x + (size_t)row * F_IN;
    const float* wr = w + j * F_IN;
    float acc = 0.f;
#pragma unroll 5
    for (int k = 0; k < F_IN; k += 4) {
        float4 xv = *(const float4*)(xr + k);
        float4 wv = *(const float4*)(wr + k);
        acc += xv.x * wv.x + xv.y * wv.y + xv.z * wv.z + xv.w * wv.w;
    }
    h1[row * F_HID + j] = acc;
    float di = dinv[row];
    agg1[row * F_HID + j] = b1[j] + acc * di * di;
}

// K3: per-edge scatter, thread = (edge, group of 4 features)
__global__ void k_scatter1(const int* __restrict__ src32, const int* __restrict__ dst32,
                           const float* __restrict__ dinv, const float* __restrict__ h1,
                           float* __restrict__ agg1, int E) {
    int t = blockIdx.x * blockDim.x + threadIdx.x;
    if (t >= E * 4) return;
    int e = t >> 2, g = t & 3;
    int s = src32[e], d = dst32[e];
    float n = dinv[s] * dinv[d];
    float4 v = *(const float4*)(h1 + (size_t)s * F_HID + g * 4);
    float* o = agg1 + (size_t)d * F_HID + g * 4;
    atomicAdd(o + 0, v.x * n);
    atomicAdd(o + 1, v.y * n);
    atomicAdd(o + 2, v.z * n);
    atomicAdd(o + 3, v.w * n);
}

// K4: h2 = relu(agg1) @ W2 ; out = b2 + h2 * dinv^2  (self-loop init of output)
__global__ __launch_bounds__(256) void k_gemm2(const float* __restrict__ agg1,
                                               const float* __restrict__ W2,
                                               const float* __restrict__ b2,
                                               const float* __restrict__ dinv,
                                               float* __restrict__ h2,
                                               float* __restrict__ out, int N) {
    __shared__ float w[F_HID * F_OUT];
    if (threadIdx.x < F_HID * F_OUT) w[threadIdx.x] = W2[threadIdx.x];
    __syncthreads();
    int row = blockIdx.x * 256 + threadIdx.x;
    if (row >= N) return;
    const float* r = agg1 + (size_t)row * F_HID;
    float a0 = 0.f, a1 = 0.f, a2 = 0.f;
#pragma unroll
    for (int k = 0; k < F_HID; ++k) {
        float v = fmaxf(r[k], 0.f);
        a0 += v * w[k * 3 + 0];
        a1 += v * w[k * 3 + 1];
        a2 += v * w[k * 3 + 2];
    }
    h2[row * 3 + 0] = a0;
    h2[row * 3 + 1] = a1;
    h2[row * 3 + 2] = a2;
    float di = dinv[row];
    float sc = di * di;
    out[row * 3 + 0] = b2[0] + a0 * sc;
    out[row * 3 + 1] = b2[1] + a1 * sc;
    out[row * 3 + 2] = b2[2] + a2 * sc;
}

// K5: per-edge scatter into output (3 features)
__global__ void k_scatter2(const int* __restrict__ src32, const int* __restrict__ dst32,
                           const float* __restrict__ dinv, const float* __restrict__ h2,
                           float* __restrict__ out, int E) {
    int e = blockIdx.x * blockDim.x + threadIdx.x;
    if (e >= E) return;
    int s = src32[e], d = dst32[e];
    float n = dinv[s] * dinv[d];
    atomicAdd(&out[(size_t)d * 3 + 0], h2[(size_t)s * 3 + 0] * n);
    atomicAdd(&out[(size_t)d * 3 + 1], h2[(size_t)s * 3 + 1] * n);
    atomicAdd(&out[(size_t)d * 3 + 2], h2[(size_t)s * 3 + 2] * n);
}

// K6: in-place log_softmax over 3 classes
__global__ void k_lsm(float* __restrict__ out, int N) {
    int i = blockIdx.x * blockDim.x + threadIdx.x;
    if (i >= N) return;
    float a = out[i * 3 + 0], b = out[i * 3 + 1], c = out[i * 3 + 2];
    float m = fmaxf(a, fmaxf(b, c));
    float l = logf(expf(a - m) + expf(b - m) + expf(c - m));
    out[i * 3 + 0] = a - m - l;
    out[i * 3 + 1] = b - m - l;
    out[i * 3 + 2] = c - m - l;
}

extern "C" void kernel_launch(void* const* d_in, const int* in_sizes, int n_in,
                              void* d_out, int out_size, void* d_ws, size_t ws_size,
                              hipStream_t stream) {
    const float* x = (const float*)d_in[0];
    const int* ei = (const int*)d_in[1];     // harness delivers integer inputs as int32
    const float* W1 = (const float*)d_in[2];
    const float* b1 = (const float*)d_in[3];
    const float* W2 = (const float*)d_in[4];
    const float* b2 = (const float*)d_in[5];
    float* out = (float*)d_out;

    const int N = in_sizes[0] / F_IN;   // 100000
    const int E = in_sizes[1] / 2;      // 3200000

    // workspace layout (all 256B-aligned); total ~40 MB
    char* p = (char*)d_ws;
    auto alloc = [&](size_t bytes) {
        char* r = p;
        p += (bytes + 255) & ~(size_t)255;
        return r;
    };
    float* deg  = (float*)alloc((size_t)N * 4);          // deg -> dinv in place
    int* src32  = (int*)alloc((size_t)E * 4);
    int* dst32  = (int*)alloc((size_t)E * 4);
    float* h1   = (float*)alloc((size_t)N * F_HID * 4);
    float* agg1 = (float*)alloc((size_t)N * F_HID * 4);
    float* h2   = (float*)alloc((size_t)N * F_OUT * 4);

    hipMemsetAsync(deg, 0, (size_t)N * 4, stream);

    k_edges<<<(E + 255) / 256, 256, 0, stream>>>(ei, E, N, src32, dst32, deg);
    k_dinv<<<(N + 255) / 256, 256, 0, stream>>>(deg, N);
    k_gemm1<<<(N + 15) / 16, 256, 0, stream>>>(x, W1, b1, deg, h1, agg1, N);
    k_scatter1<<<((size_t)E * 4 + 255) / 256, 256, 0, stream>>>(src32, dst32, deg, h1, agg1, E);
    k_gemm2<<<(N + 255) / 256, 256, 0, stream>>>(agg1, W2, b2, deg, h2, out, N);
    k_scatter2<<<(E + 255) / 256, 256, 0, stream>>>(src32, dst32, deg, h2, out, E);
    k_lsm<<<(N + 255) / 256, 256, 0, stream>>>(out, N);
}

// Round 3
// 650.263 us; speedup vs baseline: 2.1804x; 2.1804x over previous
//
#include <hip/hip_runtime.h>

#define F_IN 500
#define F_HID 16
#define F_OUT 3

__device__ __forceinline__ int clampi(int v, int lo, int hi) {
    return min(max(v, lo), hi);
}

// K0: count in-degree with int atomics (L2-coalesced by HW)
__global__ void k_count(const int* __restrict__ ei, int E, int N, int* __restrict__ degi) {
    int e = blockIdx.x * blockDim.x + threadIdx.x;
    if (e >= E) return;
    int d = clampi(ei[(size_t)E + e], 0, N - 1);
    atomicAdd(&degi[d], 1);
}

// K1: dinv = rsqrt(deg + 1)  (self-loop contributes the +1)
__global__ void k_dinv(const int* __restrict__ degi, float* __restrict__ dinv, int N) {
    int i = blockIdx.x * blockDim.x + threadIdx.x;
    if (i >= N) return;
    dinv[i] = rsqrtf((float)degi[i] + 1.0f);
}

// K2a: per-block sums of degi (block = 256 nodes)
__global__ __launch_bounds__(256) void k_blocksum(const int* __restrict__ degi, int N,
                                                  int* __restrict__ bsum) {
    __shared__ int s[256];
    int t = threadIdx.x;
    int i = blockIdx.x * 256 + t;
    s[t] = (i < N) ? degi[i] : 0;
    __syncthreads();
    for (int off = 128; off > 0; off >>= 1) {
        if (t < off) s[t] += s[t + off];
        __syncthreads();
    }
    if (t == 0) bsum[blockIdx.x] = s[0];
}

// K2b: exclusive scan of block sums (single block, 512 threads, NB <= 512)
__global__ __launch_bounds__(512) void k_scantop(const int* __restrict__ bsum, int NB,
                                                 int* __restrict__ boff,
                                                 int* __restrict__ rowstart, int N) {
    __shared__ int s[512];
    int t = threadIdx.x;
    int v = (t < NB) ? bsum[t] : 0;
    s[t] = v;
    __syncthreads();
    for (int off = 1; off < 512; off <<= 1) {
        int add = (t >= off) ? s[t - off] : 0;
        __syncthreads();
        s[t] += add;
        __syncthreads();
    }
    if (t < NB) boff[t] = s[t] - v;   // exclusive
    if (t == NB - 1) rowstart[N] = s[t];  // total edge count
}

// K2c: per-block exclusive scan -> rowstart + cursor init
__global__ __launch_bounds__(256) void k_scanlocal(const int* __restrict__ degi, int N,
                                                   const int* __restrict__ boff,
                                                   int* __restrict__ rowstart,
                                                   int* __restrict__ cursor) {
    __shared__ int s[256];
    int t = threadIdx.x;
    int i = blockIdx.x * 256 + t;
    int v = (i < N) ? degi[i] : 0;
    s[t] = v;
    __syncthreads();
    for (int off = 1; off < 256; off <<= 1) {
        int add = (t >= off) ? s[t - off] : 0;
        __syncthreads();
        s[t] += add;
        __syncthreads();
    }
    if (i < N) {
        int start = boff[blockIdx.x] + s[t] - v;
        rowstart[i] = start;
        cursor[i] = start;
    }
}

// K3: bucket-fill CSR: ebuf[pos] = src for edges grouped by dst (int atomics only)
__global__ void k_fill(const int* __restrict__ ei, int E, int N,
                       int* __restrict__ cursor, int* __restrict__ ebuf) {
    int e = blockIdx.x * blockDim.x + threadIdx.x;
    if (e >= E) return;
    int s = clampi(ei[e], 0, N - 1);
    int d = clampi(ei[(size_t)E + e], 0, N - 1);
    int pos = atomicAdd(&cursor[d], 1);
    ebuf[pos] = s;
}

// K4: hs1 = (x @ W1) * dinv[row]   (pre-scaled messages)
// block = 256 (4 waves), wave handles 4 rows x 16 cols. W1^T staged in LDS.
__global__ __launch_bounds__(256) void k_gemm1(const float* __restrict__ x,
                                               const float* __restrict__ W1,
                                               const float* __restrict__ dinv,
                                               float* __restrict__ hs1, int N) {
    __shared__ float w[F_HID * F_IN];  // w[j][k], 32000 B
    for (int idx = threadIdx.x; idx < F_IN * F_HID; idx += 256) {
        int k = idx >> 4, j = idx & 15;
        w[j * F_IN + k] = W1[idx];
    }
    __syncthreads();
    int wave = threadIdx.x >> 6, lane = threadIdx.x & 63;
    int rsub = lane >> 4, j = lane & 15;
    int row = blockIdx.x * 16 + wave * 4 + rsub;
    if (row >= N) return;
    const float* xr = x + (size_t)row * F_IN;
    const float* wr = w + j * F_IN;
    float acc = 0.f;
#pragma unroll 5
    for (int k = 0; k < F_IN; k += 4) {
        float4 xv = *(const float4*)(xr + k);
        float4 wv = *(const float4*)(wr + k);
        acc += xv.x * wv.x + xv.y * wv.y + xv.z * wv.z + xv.w * wv.w;
    }
    hs1[row * F_HID + j] = acc * dinv[row];
}

// K5: agg1[d] = relu(b1 + dinv[d] * (hs1[d] + sum_{src->d} hs1[src]))
// one wave per node: 4 edge-slots x 16 features, shuffle-reduce across slots
__global__ __launch_bounds__(256) void k_agg1(const int* __restrict__ rowstart,
                                              const int* __restrict__ ebuf,
                                              const float* __restrict__ hs1,
                                              const float* __restrict__ b1,
                                              const float* __restrict__ dinv,
                                              float* __restrict__ agg1, int N) {
    int wave = threadIdx.x >> 6, lane = threadIdx.x & 63;
    int node = blockIdx.x * 4 + wave;
    if (node >= N) return;
    int slot = lane >> 4, j = lane & 15;
    int start = rowstart[node], end = rowstart[node + 1];
    float acc = 0.f;
    for (int i = start + slot; i < end; i += 4) {
        int s = ebuf[i];
        acc += hs1[(size_t)s * F_HID + j];
    }
    acc += __shfl_xor(acc, 16);
    acc += __shfl_xor(acc, 32);
    if (slot == 0) {
        float v = b1[j] + dinv[node] * (hs1[(size_t)node * F_HID + j] + acc);
        agg1[(size_t)node * F_HID + j] = fmaxf(v, 0.f);  // relu fused
    }
}

// K6: hs2 = (agg1 @ W2) * dinv[row]   (agg1 already relu'd)
__global__ __launch_bounds__(256) void k_gemm2(const float* __restrict__ agg1,
                                               const float* __restrict__ W2,
                                               const float* __restrict__ dinv,
                                               float* __restrict__ hs2, int N) {
    __shared__ float w[F_HID * F_OUT];
    if (threadIdx.x < F_HID * F_OUT) w[threadIdx.x] = W2[threadIdx.x];
    __syncthreads();
    int row = blockIdx.x * 256 + threadIdx.x;
    if (row >= N) return;
    const float* r = agg1 + (size_t)row * F_HID;
    float a0 = 0.f, a1 = 0.f, a2 = 0.f;
#pragma unroll
    for (int k = 0; k < F_HID; ++k) {
        float v = r[k];
        a0 += v * w[k * 3 + 0];
        a1 += v * w[k * 3 + 1];
        a2 += v * w[k * 3 + 2];
    }
    float di = dinv[row];
    hs2[(size_t)row * 3 + 0] = a0 * di;
    hs2[(size_t)row * 3 + 1] = a1 * di;
    hs2[(size_t)row * 3 + 2] = a2 * di;
}

// K7: out[d] = log_softmax(b2 + dinv[d] * (hs2[d] + sum hs2[src]))
// one wave per node: 16 edge-slots x 4 lanes (class c = lane&3, c==3 idle)
__global__ __launch_bounds__(256) void k_agg2(const int* __restrict__ rowstart,
                                              const int* __restrict__ ebuf,
                                              const float* __restrict__ hs2,
                                              const float* __restrict__ b2,
                                              const float* __restrict__ dinv,
                                              float* __restrict__ out, int N) {
    int wave = threadIdx.x >> 6, lane = threadIdx.x & 63;
    int node = blockIdx.x * 4 + wave;
    if (node >= N) return;
    int slot = lane >> 2, c = lane & 3;
    int start = rowstart[node], end = rowstart[node + 1];
    float acc = 0.f;
    for (int i = start + slot; i < end; i += 16) {
        int s = ebuf[i];
        if (c < 3) acc += hs2[(size_t)s * 3 + c];
    }
    // reduce across 16 slots (stride 4 in lane space), c kept fixed
    acc += __shfl_xor(acc, 4);
    acc += __shfl_xor(acc, 8);
    acc += __shfl_xor(acc, 16);
    acc += __shfl_xor(acc, 32);
    float v = 0.f;
    if (c < 3) v = b2[c] + dinv[node] * (hs2[(size_t)node * 3 + c] + acc);
    float a0 = __shfl(v, 0), a1 = __shfl(v, 1), a2 = __shfl(v, 2);
    float m = fmaxf(a0, fmaxf(a1, a2));
    float l = logf(expf(a0 - m) + expf(a1 - m) + expf(a2 - m));
    if (lane < 3) out[(size_t)node * 3 + lane] = v - m - l;
}

extern "C" void kernel_launch(void* const* d_in, const int* in_sizes, int n_in,
                              void* d_out, int out_size, void* d_ws, size_t ws_size,
                              hipStream_t stream) {
    const float* x = (const float*)d_in[0];
    const int* ei = (const int*)d_in[1];     // int32 per harness
    const float* W1 = (const float*)d_in[2];
    const float* b1 = (const float*)d_in[3];
    const float* W2 = (const float*)d_in[4];
    const float* b2 = (const float*)d_in[5];
    float* out = (float*)d_out;

    const int N = in_sizes[0] / F_IN;   // 100000
    const int E = in_sizes[1] / 2;      // 3200000
    const int NB = (N + 255) / 256;     // 391

    // workspace layout (~28 MB)
    char* p = (char*)d_ws;
    auto alloc = [&](size_t bytes) {
        char* r = p;
        p += (bytes + 255) & ~(size_t)255;
        return r;
    };
    int*   degi     = (int*)alloc((size_t)N * 4);
    float* dinv     = (float*)alloc((size_t)N * 4);
    int*   rowstart = (int*)alloc(((size_t)N + 1) * 4);
    int*   cursor   = (int*)alloc((size_t)N * 4);
    int*   bsum     = (int*)alloc((size_t)NB * 4);
    int*   boff     = (int*)alloc((size_t)NB * 4);
    int*   ebuf     = (int*)alloc((size_t)E * 4);
    float* hs1      = (float*)alloc((size_t)N * F_HID * 4);
    float* agg1     = (float*)alloc((size_t)N * F_HID * 4);
    float* hs2      = (float*)alloc((size_t)N * F_OUT * 4);

    hipMemsetAsync(degi, 0, (size_t)N * 4, stream);

    k_count<<<(E + 255) / 256, 256, 0, stream>>>(ei, E, N, degi);
    k_dinv<<<(N + 255) / 256, 256, 0, stream>>>(degi, dinv, N);
    k_blocksum<<<NB, 256, 0, stream>>>(degi, N, bsum);
    k_scantop<<<1, 512, 0, stream>>>(bsum, NB, boff, rowstart, N);
    k_scanlocal<<<NB, 256, 0, stream>>>(degi, N, boff, rowstart, cursor);
    k_fill<<<(E + 255) / 256, 256, 0, stream>>>(ei, E, N, cursor, ebuf);
    k_gemm1<<<(N + 15) / 16, 256, 0, stream>>>(x, W1, dinv, hs1, N);
    k_agg1<<<(N + 3) / 4, 256, 0, stream>>>(rowstart, ebuf, hs1, b1, dinv, agg1, N);
    k_gemm2<<<(N + 255) / 256, 256, 0, stream>>>(agg1, W2, dinv, hs2, N);
    k_agg2<<<(N + 3) / 4, 256, 0, stream>>>(rowstart, ebuf, hs2, b2, dinv, out, N);
}